// Round 15
// baseline (124.387 us; speedup 1.0000x reference)
//
#include <hip/hip_runtime.h>

typedef __attribute__((ext_vector_type(4))) float f4;
typedef __attribute__((ext_vector_type(4))) float f32x4;
typedef __attribute__((ext_vector_type(8))) __bf16 bf8;
typedef __attribute__((ext_vector_type(8))) unsigned short us8;

#define NB 64
#define LSEQ 40
#define D_DIM 768
#define NPATCH 576
#define SEQ 617
#define K_DIM 768
#define M_DIM (NB * NPATCH)   // 36864
#define GEMM_LDS 98304

static __device__ __forceinline__ unsigned short f2bf(float f) {
    union { float f; unsigned u; } v; v.f = f;
    unsigned r = v.u + 0x7FFFu + ((v.u >> 16) & 1u);
    return (unsigned short)(r >> 16);
}

static __device__ __forceinline__ void gload_lds16(const void* g, void* l) {
    __builtin_amdgcn_global_load_lds(
        (const __attribute__((address_space(1))) unsigned int*)g,
        (__attribute__((address_space(3))) unsigned int*)l,
        16, 0, 0);
}

#define MFMA16(a, b, c) __builtin_amdgcn_mfma_f32_16x16x32_bf16((a), (b), (c), 0, 0, 0)

// ---- prep: convert_w only (f32 -> bf16, chunk-swizzled) ----
// stored[n][blk][c] = logical[n][blk][c ^ (n&7)], 16B chunks, 128B blocks.
__global__ __launch_bounds__(256) void prep_w(const float* __restrict__ cw,
                                              unsigned short* __restrict__ wo) {
    int t = blockIdx.x * 256 + threadIdx.x;   // 73728 chunk-threads
    int cs = t % 96, n = t / 96;
    int blk8 = cs >> 3, c = cs & 7;
    int cl = (blk8 << 3) | (c ^ (n & 7));
    const float* s = cw + (size_t)n * 768 + cl * 8;
    f4 a = *(const f4*)s;
    f4 b = *(const f4*)(s + 4);
    us8 r;
    r[0]=f2bf(a[0]); r[1]=f2bf(a[1]); r[2]=f2bf(a[2]); r[3]=f2bf(a[3]);
    r[4]=f2bf(b[0]); r[5]=f2bf(b[1]); r[6]=f2bf(b[2]); r[7]=f2bf(b[3]);
    *(us8*)(wo + (size_t)n * 768 + cs * 8) = r;
}

// ---- fused GEMM: 128x256 tile, BK=64, 8 waves each 64x64 out ----
// Same sync skeleton as R14 (proven): depth-1 reg-staged A from
// pixel_values, B via global_load_lds from pre-swizzled bf16 W, one
// __syncthreads per K-tile. Changes vs R14 (mechanism per change):
//  - acc halves (64 regs) -> compiler gets ~100 regs of scheduling
//    headroom (R8/R9 spills were acc-128 + manual deepening);
//  - LDS reads/wave/tile 24 -> 16 (-33% port pressure);
//  - per-thread A staging halves (4xf4 + 2 us8);
//  - grid 864 = 3.375 batches -> dispatch-tail waste 31% -> 11%;
//  - px traffic unchanged (3 n-sharers per px panel, XCD-adjacent).
// Post-epilogue: text rows (1/wave) + CLS/masks, acc dead by then.
__global__ __launch_bounds__(512, 2) void gemm_patch(
    const float* __restrict__ px, const __bf16* __restrict__ W,
    const float* __restrict__ conv_b, const float* __restrict__ vis_pos,
    const float* __restrict__ mod, float* __restrict__ out,
    const int* __restrict__ ids, const int* __restrict__ tti,
    const float* __restrict__ we, const float* __restrict__ pe,
    const float* __restrict__ tke, const float* __restrict__ lng,
    const float* __restrict__ lnb, const float* __restrict__ cls,
    const int* __restrict__ am) {
    extern __shared__ __align__(16) char smem[];   // 96 KB
    char* Ab0 = smem;            // A buffers: 128 rows x 128 B
    char* Ab1 = smem + 16384;
    char* Bb0 = smem + 32768;    // B buffers: 256 rows x 128 B
    char* Bb1 = smem + 65536;

    const int tid = threadIdx.x;
    const int w = tid >> 6, lane = tid & 63;

    // bijective XCD remap: 864 blocks = 8 XCDs * 108; consecutive gwi
    // share tile_m (3 n-sharers of one px panel on one XCD's L2).
    int lid = blockIdx.x;
    int gwi = (lid & 7) * 108 + (lid >> 3);
    const int tile_n = (gwi % 3) * 256;
    const int tile_m = (gwi / 3) * 128;
    const int wr = (w >> 2) * 64;        // 2 M-waves
    const int wc = (w & 3) * 64;         // 4 N-waves

    f32x4 acc[4][4] = {};
    const char* Bb = (const char*)W;
    const int rsel = lane & 15;
    const int hk = lane >> 4;

    // ---- A-staging lane geometry: 4 threads per A row ----
    const int arow = tid >> 2;           // A-tile row (patch) this thread stages
    const int q4 = tid & 3;              // image-row quarter within BK
    int agm = tile_m + arow;
    int abimg = agm / 576, ap = agm % 576;
    int aph = ap / 24, apw = ap % 24;
    const float* pxrow = px + (size_t)abimg * 442368
                            + (size_t)(aph * 16) * 384 + apw * 16;

    f4 areg[4];
    auto LOAD_A = [&](int kt) {
        int c = kt >> 2, i0 = (kt & 3) << 2;
        const float* s = pxrow + (size_t)c * 147456 + (i0 + q4) * 384;
#pragma unroll
        for (int q = 0; q < 4; ++q) areg[q] = *(const f4*)(s + q * 4);
    };
    auto WRITE_A = [&](char* dst) {
        us8 h0, h1;
#pragma unroll
        for (int q = 0; q < 2; ++q) {
            h0[q*4+0]=f2bf(areg[q][0]);   h0[q*4+1]=f2bf(areg[q][1]);
            h0[q*4+2]=f2bf(areg[q][2]);   h0[q*4+3]=f2bf(areg[q][3]);
            h1[q*4+0]=f2bf(areg[q+2][0]); h1[q*4+1]=f2bf(areg[q+2][1]);
            h1[q*4+2]=f2bf(areg[q+2][2]); h1[q*4+3]=f2bf(areg[q+2][3]);
        }
        int cc0 = q4 * 2;   // k_local chunks = i_local*2 + {0,1}
        *(us8*)(dst + arow * 128 + ((cc0    ) ^ (arow & 7)) * 16) = h0;
        *(us8*)(dst + arow * 128 + ((cc0 + 1) ^ (arow & 7)) * 16) = h1;
    };
    auto STAGE_B = [&](char* lbase, int kt) {
#pragma unroll
        for (int i = 0; i < 4; ++i) {
            int uoff = (w << 10) + i * 8192;       // wave-uniform
            int loff = uoff + (lane << 4);
            int row = loff >> 7, col = loff & 127;
            gload_lds16(Bb + (size_t)(tile_n + row) * 1536 + kt * 128 + col,
                        lbase + uoff);
        }
    };

    // prologue: tile 0
    LOAD_A(0);
    STAGE_B(Bb0, 0);
    WRITE_A(Ab0);            // compiler inserts vmcnt wait for areg
    __syncthreads();         // drains B gload_lds + A ds_writes

    for (int t = 0; t < 12; ++t) {
        char* Ac = (t & 1) ? Ab1 : Ab0;
        char* Bc = (t & 1) ? Bb1 : Bb0;
        char* An = (t & 1) ? Ab0 : Ab1;
        char* Bn = (t & 1) ? Bb0 : Bb1;

        if (t < 11) {
            LOAD_A(t + 1);       // px f32 -> regs, in flight over MFMAs
            STAGE_B(Bn, t + 1);  // bf16 W -> LDS direct
        }

        bf8 a0[4][2], b0[4][2];
#pragma unroll
        for (int mi = 0; mi < 4; ++mi) {
            int r = wr + mi * 16 + rsel;
#pragma unroll
            for (int ks = 0; ks < 2; ++ks) {
                int cst = (ks * 4 + hk) ^ (r & 7);
                a0[mi][ks] = *(const bf8*)(Ac + r * 128 + cst * 16);
            }
        }
#pragma unroll
        for (int ni = 0; ni < 4; ++ni) {
            int r = wc + ni * 16 + rsel;
#pragma unroll
            for (int ks = 0; ks < 2; ++ks) {
                int cst = (ks * 4 + hk) ^ (r & 7);
                b0[ni][ks] = *(const bf8*)(Bc + r * 128 + cst * 16);
            }
        }
#pragma unroll
        for (int mi = 0; mi < 4; ++mi)
#pragma unroll
            for (int ni = 0; ni < 4; ++ni) {
                acc[mi][ni] = MFMA16(a0[mi][0], b0[ni][0], acc[mi][ni]);
                acc[mi][ni] = MFMA16(a0[mi][1], b0[ni][1], acc[mi][ni]);
            }

        if (t < 11) {
            WRITE_A(An);         // cvt + swizzled ds_write (after MFMAs)
            __syncthreads();     // vmcnt(0)+lgkmcnt(0)+barrier: all staged
        }
    }

    // ---- epilogue: hoisted div, per-ni const folds ----
    {
        const int lr = (lane >> 4) * 4;
        const int lc = lane & 15;
        int gnv[4]; float cv[4];
#pragma unroll
        for (int ni = 0; ni < 4; ++ni) {
            gnv[ni] = tile_n + wc + ni * 16 + lc;
            cv[ni] = conv_b[gnv[ni]] + mod[768 + gnv[ni]];
        }
#pragma unroll
        for (int mi = 0; mi < 4; ++mi) {
            int gm0 = tile_m + wr + mi * 16 + lr;
            int bimg0 = gm0 / 576;
            int pp0 = gm0 - bimg0 * 576;
#pragma unroll
            for (int r = 0; r < 4; ++r) {
                int bimg = bimg0, pp2 = pp0 + r;
                if (pp2 >= 576) { bimg++; pp2 -= 576; }
                const float* vp = vis_pos + (size_t)(pp2 + 1) * 768;
                float* op = out + ((size_t)bimg * SEQ + 1 + LSEQ + pp2) * 768;
#pragma unroll
                for (int ni = 0; ni < 4; ++ni)
                    op[gnv[ni]] = acc[mi][ni][r] + cv[ni] + vp[gnv[ni]];
            }
        }
    }

    // ---- appended: text rows (1 per wave; 864*8 = 6912 slots >= 2560) ----
    {
        int row = blockIdx.x * 8 + w;
        if (row < 2560) {
            int b = row / 40, l = row % 40;
            const float* wp = we + (size_t)ids[row] * 768;
            const float* pp = pe + l * 768;
            const float* tp = tke + (size_t)tti[row] * 768;
            f4 x[3];
            float s = 0.f, q = 0.f;
#pragma unroll
            for (int j = 0; j < 3; ++j) {
                int d = j * 256 + lane * 4;
                f4 v = *(const f4*)(wp + d);
                f4 v2 = *(const f4*)(pp + d);
                f4 v3 = *(const f4*)(tp + d);
                v = v + v2 + v3;
                x[j] = v;
                s += v[0] + v[1] + v[2] + v[3];
                q += v[0]*v[0] + v[1]*v[1] + v[2]*v[2] + v[3]*v[3];
            }
#pragma unroll
            for (int o = 32; o > 0; o >>= 1) { s += __shfl_xor(s, o); q += __shfl_xor(q, o); }
            float mean = s * (1.0f / 768.0f);
            float var = q * (1.0f / 768.0f) - mean * mean;
            float rstd = rsqrtf(var + 1e-12f);
            float* op = out + ((size_t)b * SEQ + 1 + l) * 768;
#pragma unroll
            for (int j = 0; j < 3; ++j) {
                int d = j * 256 + lane * 4;
                f4 gg = *(const f4*)(lng + d);
                f4 bv = *(const f4*)(lnb + d);
                f4 mm = *(const f4*)(mod + d);
                f4 r = (x[j] - mean) * rstd * gg + bv + mm;
                *(f4*)(op + d) = r;
            }
        }
    }

    // ---- appended: CLS rows + masks (guarded flat pass) ----
    {
        int t2 = blockIdx.x * 512 + tid;     // 442368 threads >= 88640 elems
        if (t2 < NB * 768) {
            int b = t2 / 768, d = t2 % 768;
            out[(size_t)b * SEQ * 768 + d] = cls[d];
        } else if (t2 < NB * 768 + NB * SEQ) {
            int i = t2 - NB * 768;
            int b = i / SEQ, s = i % SEQ;
            float v = 1.0f;
            if (s >= 1 && s <= LSEQ) v = (float)am[b * LSEQ + s - 1];
            out[(size_t)NB * SEQ * 768 + i] = v;
        }
    }
}

extern "C" void kernel_launch(void* const* d_in, const int* in_sizes, int n_in,
                              void* d_out, int out_size, void* d_ws, size_t ws_size,
                              hipStream_t stream) {
    const int*   ids  = (const int*)d_in[0];
    const int*   am   = (const int*)d_in[1];
    const int*   tti  = (const int*)d_in[2];
    const float* px   = (const float*)d_in[3];
    const float* we   = (const float*)d_in[5];
    const float* pe   = (const float*)d_in[6];
    const float* tke  = (const float*)d_in[7];
    const float* lng  = (const float*)d_in[8];
    const float* lnb  = (const float*)d_in[9];
    const float* cw   = (const float*)d_in[10];
    const float* cb   = (const float*)d_in[11];
    const float* cls  = (const float*)d_in[12];
    const float* vpos = (const float*)d_in[13];
    const float* mod  = (const float*)d_in[14];
    float* out = (float*)d_out;

    __bf16* Wbf = (__bf16*)d_ws;

    hipFuncSetAttribute((const void*)gemm_patch,
                        hipFuncAttributeMaxDynamicSharedMemorySize, GEMM_LDS);

    prep_w<<<288, 256, 0, stream>>>(cw, (unsigned short*)Wbf);
    gemm_patch<<<864, 512, GEMM_LDS, stream>>>(px, Wbf, cb, vpos, mod, out,
                                               ids, tti, we, pe, tke, lng, lnb,
                                               cls, am);
}

// Round 16
// 101.343 us; speedup vs baseline: 1.2274x; 1.2274x over previous
//
#include <hip/hip_runtime.h>

typedef __attribute__((ext_vector_type(4))) float f4;
typedef __attribute__((ext_vector_type(4))) float f32x4;
typedef __attribute__((ext_vector_type(8))) __bf16 bf8;
typedef __attribute__((ext_vector_type(8))) unsigned short us8;

#define NB 64
#define LSEQ 40
#define D_DIM 768
#define NPATCH 576
#define SEQ 617
#define K_DIM 768
#define M_DIM (NB * NPATCH)   // 36864
#define GEMM_LDS 131072

static __device__ __forceinline__ unsigned short f2bf(float f) {
    union { float f; unsigned u; } v; v.f = f;
    unsigned r = v.u + 0x7FFFu + ((v.u >> 16) & 1u);
    return (unsigned short)(r >> 16);
}

static __device__ __forceinline__ void gload_lds16(const void* g, void* l) {
    __builtin_amdgcn_global_load_lds(
        (const __attribute__((address_space(1))) unsigned int*)g,
        (__attribute__((address_space(3))) unsigned int*)l,
        16, 0, 0);
}

#define MFMA16(a, b, c) __builtin_amdgcn_mfma_f32_16x16x32_bf16((a), (b), (c), 0, 0, 0)

// ---- prep: convert_w only (f32 -> bf16, chunk-swizzled) ----
// stored[n][blk][c] = logical[n][blk][c ^ (n&7)], 16B chunks, 128B blocks.
__global__ __launch_bounds__(256) void prep_w(const float* __restrict__ cw,
                                              unsigned short* __restrict__ wo) {
    int t = blockIdx.x * 256 + threadIdx.x;   // 73728 chunk-threads
    int cs = t % 96, n = t / 96;
    int blk8 = cs >> 3, c = cs & 7;
    int cl = (blk8 << 3) | (c ^ (n & 7));
    const float* s = cw + (size_t)n * 768 + cl * 8;
    f4 a = *(const f4*)s;
    f4 b = *(const f4*)(s + 4);
    us8 r;
    r[0]=f2bf(a[0]); r[1]=f2bf(a[1]); r[2]=f2bf(a[2]); r[3]=f2bf(a[3]);
    r[4]=f2bf(b[0]); r[5]=f2bf(b[1]); r[6]=f2bf(b[2]); r[7]=f2bf(b[3]);
    *(us8*)(wo + (size_t)n * 768 + cs * 8) = r;
}

// ---- fused GEMM (R14 config, best measured) + post-epilogue text/cls ----
// GEMM: 256x256, BK=64, 8 waves, depth-1 reg-staged A from pixel_values,
// B via global_load_lds from pre-swizzled bf16 W, one __syncthreads/tile.
// After the GEMM epilogue (acc dead): each wave handles one text row
// (blockIdx.x*8+w < 2560) with gather+LN+mod; then a guarded flat pass
// writes CLS rows + masks. No live-range overlap with the K-loop.
__global__ __launch_bounds__(512, 2) void gemm_patch(
    const float* __restrict__ px, const __bf16* __restrict__ W,
    const float* __restrict__ conv_b, const float* __restrict__ vis_pos,
    const float* __restrict__ mod, float* __restrict__ out,
    const int* __restrict__ ids, const int* __restrict__ tti,
    const float* __restrict__ we, const float* __restrict__ pe,
    const float* __restrict__ tke, const float* __restrict__ lng,
    const float* __restrict__ lnb, const float* __restrict__ cls,
    const int* __restrict__ am) {
    extern __shared__ __align__(16) char smem[];   // 128 KB
    char* Ab0 = smem;            // A buffers: 256 rows x 128 B
    char* Ab1 = smem + 32768;
    char* Bb0 = smem + 65536;    // B buffers
    char* Bb1 = smem + 98304;

    const int tid = threadIdx.x;
    const int w = tid >> 6, lane = tid & 63;

    // bijective XCD remap: 432 blocks = 8 XCDs * 54
    int lid = blockIdx.x;
    int gwi = (lid & 7) * 54 + (lid >> 3);
    const int tile_n = (gwi % 3) * 256;
    const int tile_m = (gwi / 3) * 256;
    const int wm = w >> 2, wn = w & 3;
    const int wr = wm * 128, wc = wn * 64;

    f32x4 acc[8][4] = {};
    const char* Bb = (const char*)W;
    const int rsel = lane & 15;
    const int hk = lane >> 4;

    // ---- A-staging lane geometry (constant across tiles) ----
    const int arow = tid & 255;          // A-tile row this thread stages
    const int ii0 = tid >> 8;            // half selector
    int agm = tile_m + arow;
    int abimg = agm / 576, ap = agm % 576;
    int aph = ap / 24, apw = ap % 24;
    const float* pxrow = px + (size_t)abimg * 442368
                            + (size_t)(aph * 16) * 384 + apw * 16;

    f4 areg[2][4];
    auto LOAD_A = [&](int kt) {
        int c = kt >> 2, i0 = (kt & 3) << 2;
#pragma unroll
        for (int rep = 0; rep < 2; ++rep) {
            int i = i0 + ii0 + rep * 2;
            const float* s = pxrow + (size_t)c * 147456 + i * 384;
#pragma unroll
            for (int q = 0; q < 4; ++q) areg[rep][q] = *(const f4*)(s + q * 4);
        }
    };
    auto WRITE_A = [&](char* dst) {
#pragma unroll
        for (int rep = 0; rep < 2; ++rep) {
            int ii = ii0 + rep * 2;
            us8 h0, h1;
#pragma unroll
            for (int q = 0; q < 2; ++q) {
                h0[q*4+0]=f2bf(areg[rep][q][0]); h0[q*4+1]=f2bf(areg[rep][q][1]);
                h0[q*4+2]=f2bf(areg[rep][q][2]); h0[q*4+3]=f2bf(areg[rep][q][3]);
                h1[q*4+0]=f2bf(areg[rep][q+2][0]); h1[q*4+1]=f2bf(areg[rep][q+2][1]);
                h1[q*4+2]=f2bf(areg[rep][q+2][2]); h1[q*4+3]=f2bf(areg[rep][q+2][3]);
            }
            int cc0 = ii * 2;
            *(us8*)(dst + arow * 128 + ((cc0    ) ^ (arow & 7)) * 16) = h0;
            *(us8*)(dst + arow * 128 + ((cc0 + 1) ^ (arow & 7)) * 16) = h1;
        }
    };
    auto STAGE_B = [&](char* lbase, int kt) {
#pragma unroll
        for (int i = 0; i < 4; ++i) {
            int uoff = (w << 10) + i * 8192;       // wave-uniform
            int loff = uoff + (lane << 4);
            int row = loff >> 7, col = loff & 127;
            gload_lds16(Bb + (size_t)(tile_n + row) * 1536 + kt * 128 + col,
                        lbase + uoff);
        }
    };

    // prologue: tile 0
    LOAD_A(0);
    STAGE_B(Bb0, 0);
    WRITE_A(Ab0);            // compiler inserts vmcnt wait for areg
    __syncthreads();         // drains B gload_lds + A ds_writes

    for (int t = 0; t < 12; ++t) {
        char* Ac = (t & 1) ? Ab1 : Ab0;
        char* Bc = (t & 1) ? Bb1 : Bb0;
        char* An = (t & 1) ? Ab0 : Ab1;
        char* Bn = (t & 1) ? Bb0 : Bb1;

        if (t < 11) {
            LOAD_A(t + 1);       // f32 pixel loads -> regs, in flight over MFMAs
            STAGE_B(Bn, t + 1);  // bf16 W -> LDS direct
        }

        bf8 a0[4][2], b0[4][2];
#pragma unroll
        for (int mi = 0; mi < 4; ++mi) {
            int r = wr + mi * 16 + rsel;
#pragma unroll
            for (int ks = 0; ks < 2; ++ks) {
                int cst = (ks * 4 + hk) ^ (r & 7);
                a0[mi][ks] = *(const bf8*)(Ac + r * 128 + cst * 16);
            }
        }
#pragma unroll
        for (int ni = 0; ni < 4; ++ni) {
            int r = wc + ni * 16 + rsel;
#pragma unroll
            for (int ks = 0; ks < 2; ++ks) {
                int cst = (ks * 4 + hk) ^ (r & 7);
                b0[ni][ks] = *(const bf8*)(Bc + r * 128 + cst * 16);
            }
        }
#pragma unroll
        for (int mi = 0; mi < 4; ++mi)
#pragma unroll
            for (int ni = 0; ni < 4; ++ni) {
                acc[mi][ni] = MFMA16(a0[mi][0], b0[ni][0], acc[mi][ni]);
                acc[mi][ni] = MFMA16(a0[mi][1], b0[ni][1], acc[mi][ni]);
            }

        bf8 a1[4][2];
#pragma unroll
        for (int mi = 0; mi < 4; ++mi) {
            int r = wr + 64 + mi * 16 + rsel;
#pragma unroll
            for (int ks = 0; ks < 2; ++ks) {
                int cst = (ks * 4 + hk) ^ (r & 7);
                a1[mi][ks] = *(const bf8*)(Ac + r * 128 + cst * 16);
            }
        }
#pragma unroll
        for (int mi = 0; mi < 4; ++mi)
#pragma unroll
            for (int ni = 0; ni < 4; ++ni) {
                acc[4 + mi][ni] = MFMA16(a1[mi][0], b0[ni][0], acc[4 + mi][ni]);
                acc[4 + mi][ni] = MFMA16(a1[mi][1], b0[ni][1], acc[4 + mi][ni]);
            }

        if (t < 11) {
            WRITE_A(An);         // cvt + swizzled ds_write (after MFMAs)
            __syncthreads();     // vmcnt(0)+lgkmcnt(0)+barrier: all staged
        }
    }

    // ---- epilogue: hoisted div, per-ni const folds ----
    {
        const int lr = (lane >> 4) * 4;
        const int lc = lane & 15;
        int gnv[4]; float cv[4];
#pragma unroll
        for (int ni = 0; ni < 4; ++ni) {
            gnv[ni] = tile_n + wc + ni * 16 + lc;
            cv[ni] = conv_b[gnv[ni]] + mod[768 + gnv[ni]];
        }
#pragma unroll
        for (int mi = 0; mi < 8; ++mi) {
            int gm0 = tile_m + wr + mi * 16 + lr;
            int bimg0 = gm0 / 576;
            int pp0 = gm0 - bimg0 * 576;
#pragma unroll
            for (int r = 0; r < 4; ++r) {
                int bimg = bimg0, pp2 = pp0 + r;
                if (pp2 >= 576) { bimg++; pp2 -= 576; }
                const float* vp = vis_pos + (size_t)(pp2 + 1) * 768;
                float* op = out + ((size_t)bimg * SEQ + 1 + LSEQ + pp2) * 768;
#pragma unroll
                for (int ni = 0; ni < 4; ++ni)
                    op[gnv[ni]] = acc[mi][ni][r] + cv[ni] + vp[gnv[ni]];
            }
        }
    }

    // ---- appended: text rows (1 per wave; 432*8 = 3456 slots >= 2560) ----
    {
        int row = blockIdx.x * 8 + w;
        if (row < 2560) {
            int b = row / 40, l = row % 40;
            const float* wp = we + (size_t)ids[row] * 768;
            const float* pp = pe + l * 768;
            const float* tp = tke + (size_t)tti[row] * 768;
            f4 x[3];
            float s = 0.f, q = 0.f;
#pragma unroll
            for (int j = 0; j < 3; ++j) {
                int d = j * 256 + lane * 4;
                f4 v = *(const f4*)(wp + d);
                f4 v2 = *(const f4*)(pp + d);
                f4 v3 = *(const f4*)(tp + d);
                v = v + v2 + v3;
                x[j] = v;
                s += v[0] + v[1] + v[2] + v[3];
                q += v[0]*v[0] + v[1]*v[1] + v[2]*v[2] + v[3]*v[3];
            }
#pragma unroll
            for (int o = 32; o > 0; o >>= 1) { s += __shfl_xor(s, o); q += __shfl_xor(q, o); }
            float mean = s * (1.0f / 768.0f);
            float var = q * (1.0f / 768.0f) - mean * mean;
            float rstd = rsqrtf(var + 1e-12f);
            float* op = out + ((size_t)b * SEQ + 1 + l) * 768;
#pragma unroll
            for (int j = 0; j < 3; ++j) {
                int d = j * 256 + lane * 4;
                f4 gg = *(const f4*)(lng + d);
                f4 bv = *(const f4*)(lnb + d);
                f4 mm = *(const f4*)(mod + d);
                f4 r = (x[j] - mean) * rstd * gg + bv + mm;
                *(f4*)(op + d) = r;
            }
        }
    }

    // ---- appended: CLS rows + masks (guarded flat pass) ----
    {
        int t2 = blockIdx.x * 512 + tid;     // 221184 threads >= 88640 elems
        if (t2 < NB * 768) {
            int b = t2 / 768, d = t2 % 768;
            out[(size_t)b * SEQ * 768 + d] = cls[d];
        } else if (t2 < NB * 768 + NB * SEQ) {
            int i = t2 - NB * 768;
            int b = i / SEQ, s = i % SEQ;
            float v = 1.0f;
            if (s >= 1 && s <= LSEQ) v = (float)am[b * LSEQ + s - 1];
            out[(size_t)NB * SEQ * 768 + i] = v;
        }
    }
}

extern "C" void kernel_launch(void* const* d_in, const int* in_sizes, int n_in,
                              void* d_out, int out_size, void* d_ws, size_t ws_size,
                              hipStream_t stream) {
    const int*   ids  = (const int*)d_in[0];
    const int*   am   = (const int*)d_in[1];
    const int*   tti  = (const int*)d_in[2];
    const float* px   = (const float*)d_in[3];
    const float* we   = (const float*)d_in[5];
    const float* pe   = (const float*)d_in[6];
    const float* tke  = (const float*)d_in[7];
    const float* lng  = (const float*)d_in[8];
    const float* lnb  = (const float*)d_in[9];
    const float* cw   = (const float*)d_in[10];
    const float* cb   = (const float*)d_in[11];
    const float* cls  = (const float*)d_in[12];
    const float* vpos = (const float*)d_in[13];
    const float* mod  = (const float*)d_in[14];
    float* out = (float*)d_out;

    __bf16* Wbf = (__bf16*)d_ws;

    hipFuncSetAttribute((const void*)gemm_patch,
                        hipFuncAttributeMaxDynamicSharedMemorySize, GEMM_LDS);

    prep_w<<<288, 256, 0, stream>>>(cw, (unsigned short*)Wbf);
    gemm_patch<<<432, 512, GEMM_LDS, stream>>>(px, Wbf, cb, vpos, mod, out,
                                               ids, tti, we, pe, tke, lng, lnb,
                                               cls, am);
}